// Round 3
// baseline (290.078 us; speedup 1.0000x reference)
//
#include <hip/hip_runtime.h>
#include <hip/hip_cooperative_groups.h>
#include <cfloat>
#include <math.h>

namespace cg = cooperative_groups;

#define IMG_B 16
#define IMG_H 1024
#define IMG_W 1280
#define NPIX (IMG_H * IMG_W)          // 1,310,720
#define BINS 256
#define SLICES 64                     // slices per image (16 rows each)
#define NBLK (IMG_B * SLICES)         // 1024
#define F4_PER_SLICE (16 * IMG_W / 4) // 5120

// ---------- helpers ----------
__device__ __forceinline__ unsigned encf(float f) {
    unsigned u = __float_as_uint(f);
    return (u >> 31) ? ~u : (u | 0x80000000u);
}
__device__ __forceinline__ float decf(unsigned u) {
    unsigned b = (u & 0x80000000u) ? (u & 0x7fffffffu) : ~u;
    return __uint_as_float(b);
}

// ws layout (bytes):
//   mmp   : uint2[1024]      @ 0       per-slice (min,max) encoded       8 KB
//   mom   : double[1024*4]   @ 8192    per-slice S,S2,LS,LS2            32 KB
//   bhist : uint[1024*256]   @ 40960   per-slice fixed-point histogram   1 MB
// All fully overwritten every call -> no init kernel needed.

// ===== Cooperative kernel: phase1 (pre) -> grid.sync -> phase2 (hist) ======
// Phase 1 is byte-identical to the verified k_pre body; phase 2 to k_hist.
// One grid-wide barrier replaces a kernel boundary, so the image is read cold
// exactly once and re-read L3-warm once — the separate k_minmax pass is gone.
// __launch_bounds__(256,4): 4 waves/EU -> VGPR<=128 -> 4 blocks/CU guaranteed,
// so the 1024-block cooperative launch always fits (256 CUs * 4).
__global__ __launch_bounds__(256, 4) void k_fused12(
    const float* __restrict__ img,
    uint2* __restrict__ mmp,
    double* __restrict__ mom,
    unsigned* __restrict__ bhist)
{
    const int blk = blockIdx.x;
    const int tid = threadIdx.x;
    const int b   = blk >> 6;           // image
    const int sl  = blk & 63;           // slice (16 rows)
    const int lane = tid & 63, wv = tid >> 6;

    __shared__ float swred[4][4];
    __shared__ float rmn[4], rmx[4];
    __shared__ unsigned long long lh64[BINS + 1];
    __shared__ float sh_ab[2];

    // ---------------- phase 1: min/max + moments + Laplacian ----------------
    {
        const float* base = img + (size_t)b * NPIX;
        const int r0 = sl * 16;

        float fs = 0.f, fs2 = 0.f, fls = 0.f, fls2 = 0.f;
        float fmn = FLT_MAX, fmx = -FLT_MAX;

        #pragma unroll 2
        for (int k = 0; k < 20; ++k) {               // 20*256 = 5120 float4
            int i   = tid + k * 256;
            int ri  = i / 320;                        // row within slice
            int c   = i - ri * 320;                   // float4 col 0..319
            int r   = r0 + ri;
            const float* rowf = base + (size_t)r * IMG_W;
            float4 m = ((const float4*)rowf)[c];
            float4 up = make_float4(0.f, 0.f, 0.f, 0.f);
            float4 dn = make_float4(0.f, 0.f, 0.f, 0.f);
            if (r > 0)          up = ((const float4*)(rowf - IMG_W))[c];
            if (r < IMG_H - 1)  dn = ((const float4*)(rowf + IMG_W))[c];
            float lft = (c > 0)   ? rowf[4 * c - 1] : 0.f;
            float rgt = (c < 319) ? rowf[4 * c + 4] : 0.f;

            fs  += (m.x + m.y) + (m.z + m.w);
            fs2 += (m.x * m.x + m.y * m.y) + (m.z * m.z + m.w * m.w);
            fmn = fminf(fmn, fminf(fminf(m.x, m.y), fminf(m.z, m.w)));
            fmx = fmaxf(fmx, fmaxf(fmaxf(m.x, m.y), fmaxf(m.z, m.w)));

            float l0 = up.x + dn.x + lft + m.y - 4.f * m.x;
            float l1 = up.y + dn.y + m.x + m.z - 4.f * m.y;
            float l2 = up.z + dn.z + m.y + m.w - 4.f * m.z;
            float l3 = up.w + dn.w + m.z + rgt - 4.f * m.w;
            fls  += (l0 + l1) + (l2 + l3);
            fls2 += (l0 * l0 + l1 * l1) + (l2 * l2 + l3 * l3);
        }

        for (int o = 32; o; o >>= 1) {
            fs   += __shfl_down(fs,   (unsigned)o, 64);
            fs2  += __shfl_down(fs2,  (unsigned)o, 64);
            fls  += __shfl_down(fls,  (unsigned)o, 64);
            fls2 += __shfl_down(fls2, (unsigned)o, 64);
            fmn = fminf(fmn, __shfl_down(fmn, (unsigned)o, 64));
            fmx = fmaxf(fmx, __shfl_down(fmx, (unsigned)o, 64));
        }
        if (lane == 0) {
            swred[0][wv] = fs;  swred[1][wv] = fs2;
            swred[2][wv] = fls; swred[3][wv] = fls2;
            rmn[wv] = fmn; rmx[wv] = fmx;
        }
        __syncthreads();
        if (tid == 0) {
            double S   = (double)swred[0][0] + (double)swred[0][1] + (double)swred[0][2] + (double)swred[0][3];
            double S2  = (double)swred[1][0] + (double)swred[1][1] + (double)swred[1][2] + (double)swred[1][3];
            double LS  = (double)swred[2][0] + (double)swred[2][1] + (double)swred[2][2] + (double)swred[2][3];
            double LS2 = (double)swred[3][0] + (double)swred[3][1] + (double)swred[3][2] + (double)swred[3][3];
            mom[blk * 4 + 0] = S;  mom[blk * 4 + 1] = S2;
            mom[blk * 4 + 2] = LS; mom[blk * 4 + 3] = LS2;
            float mn = fminf(fminf(rmn[0], rmn[1]), fminf(rmn[2], rmn[3]));
            float mx = fmaxf(fmaxf(rmx[0], rmx[1]), fmaxf(rmx[2], rmx[3]));
            mmp[blk] = make_uint2(encf(mn), encf(mx));
        }
    }

    // ---------------- grid-wide barrier (the only one) ----------------------
    cg::this_grid().sync();

    // ---------------- phase 2: packed-u64 soft histogram --------------------
    // image min/max from the 64 slice partials
    if (tid < 64) {
        uint2 e = mmp[b * 64 + tid];
        unsigned emn = e.x, emx = e.y;
        for (int o = 32; o; o >>= 1) {
            emn = min(emn, (unsigned)__shfl_down(emn, (unsigned)o, 64));
            emx = max(emx, (unsigned)__shfl_down(emx, (unsigned)o, 64));
        }
        if (tid == 0) {
            float fmn = decf(emn), fmx = decf(emx);
            float rng = fmx - fmn;
            if (rng == 0.f) rng = 1.f;
            float a = 256.f / rng;                 // pp = v*a + bb
            float bb = -fmn * a - 0.5f;
            sh_ab[0] = a; sh_ab[1] = bb;
        }
    }
    lh64[tid] = 0ull;
    if (tid == 0) lh64[BINS] = 0ull;
    __syncthreads();

    const float a = sh_ab[0], bb = sh_ab[1];

    const float4* p = (const float4*)img + (size_t)blk * F4_PER_SLICE;
    #pragma unroll 2
    for (int k = 0; k < 20; ++k) {               // 20*256 = 5120 float4
        float4 v = p[tid + k * 256];
        #pragma unroll
        for (int j = 0; j < 4; ++j) {
            float vv = (j == 0) ? v.x : (j == 1) ? v.y : (j == 2) ? v.z : v.w;
            float pp = fminf(fmaxf(vv * a + bb, -0.5f), 255.5f);
            float fi = floorf(pp);
            int   i0 = (int)fi;                   // -1 .. 255
            unsigned w1q = (unsigned)((pp - fi) * 65536.f + 0.5f);
            atomicAdd(&lh64[i0 + 1], 0x100000000ull + (unsigned long long)w1q);
        }
    }
    __syncthreads();

    unsigned long long a0 = lh64[tid];
    unsigned long long a1 = lh64[tid + 1];
    unsigned long long h  = ((a1 >> 32) << 16) - (a1 & 0xffffffffull) + (a0 & 0xffffffffull);
    bhist[blk * BINS + tid] = (unsigned)h;       // < 2^31, contention-free
}

// ===================== Kernel 2: reduce + feats + MLP ======================
__global__ __launch_bounds__(256) void k_final(
    const unsigned* __restrict__ bhist, const double* __restrict__ mom,
    const uint2* __restrict__ mmp,
    const float* __restrict__ W1, const float* __restrict__ b1,
    const float* __restrict__ W2, const float* __restrict__ b2,
    const float* __restrict__ W3, const float* __restrict__ b3,
    float* __restrict__ out)
{
    const int ib = blockIdx.x;    // image
    const int tid = threadIdx.x;
    const int lane = tid & 63, wv = tid >> 6;

    __shared__ double dred[4];
    __shared__ float  fred[4];
    __shared__ double smom[4];
    __shared__ unsigned smm2[2];
    __shared__ unsigned sgm[4];
    __shared__ float f5[5], h1[64], h2[64], lg[3];

    // per-bin total over 64 slice histograms (exact in double)
    double h = 0.0;
    for (int s = 0; s < 64; ++s)
        h += (double)bhist[(ib * 64 + s) * BINS + tid];

    double tot = h;
    for (int o = 32; o; o >>= 1) tot += __shfl_down(tot, (unsigned)o, 64);
    if (lane == 0) dred[wv] = tot;
    __syncthreads();
    tot = dred[0] + dred[1] + dred[2] + dred[3];

    double hv = h * (1.0 / 65536.0);
    double tv = tot * (1.0 / 65536.0);
    float hn = (float)(hv / (tv + 1e-10));
    float ce = hn * log2f(hn + 1e-10f);
    for (int o = 32; o; o >>= 1) ce += __shfl_down(ce, (unsigned)o, 64);
    if (lane == 0) fred[wv] = ce;

    if (tid < 64) {   // moments + image min/max
        double q0 = mom[(ib * 64 + tid) * 4 + 0];
        double q1 = mom[(ib * 64 + tid) * 4 + 1];
        double q2 = mom[(ib * 64 + tid) * 4 + 2];
        double q3 = mom[(ib * 64 + tid) * 4 + 3];
        uint2 e = mmp[ib * 64 + tid];
        unsigned emn = e.x, emx = e.y;
        for (int o = 32; o; o >>= 1) {
            q0 += __shfl_down(q0, (unsigned)o, 64);
            q1 += __shfl_down(q1, (unsigned)o, 64);
            q2 += __shfl_down(q2, (unsigned)o, 64);
            q3 += __shfl_down(q3, (unsigned)o, 64);
            emn = min(emn, (unsigned)__shfl_down(emn, (unsigned)o, 64));
            emx = max(emx, (unsigned)__shfl_down(emx, (unsigned)o, 64));
        }
        if (tid == 0) {
            smom[0] = q0; smom[1] = q1; smom[2] = q2; smom[3] = q3;
            smm2[0] = emn; smm2[1] = emx;
        }
    }
    {   // global max over all 1024 slice maxima (scale decision)
        unsigned g = max(max(mmp[tid].y, mmp[256 + tid].y),
                         max(mmp[512 + tid].y, mmp[768 + tid].y));
        for (int o = 32; o; o >>= 1)
            g = max(g, (unsigned)__shfl_down(g, (unsigned)o, 64));
        if (lane == 0) sgm[wv] = g;
    }
    __syncthreads();

    if (tid == 0) {
        float ent = -(fred[0] + fred[1] + fred[2] + fred[3]) / 8.f;  // /log2(256)
        float gmax = decf(max(max(sgm[0], sgm[1]), max(sgm[2], sgm[3])));
        float sc = (gmax > 1.f) ? (1.f / 16383.f) : 1.f;
        double N = (double)NPIX;
        double S = smom[0], S2 = smom[1], LS = smom[2], LS2 = smom[3];
        double sc2 = (double)sc * (double)sc;
        float var  = (float)((S2  - S  * S  / N) / (N - 1.0) * sc2);
        float lvar = (float)((LS2 - LS * LS / N) / (N - 1.0) * sc2);
        float mn = decf(smm2[0]) * sc;
        float mx = decf(smm2[1]) * sc;
        float* fo = out + 64 + ib * 5;
        fo[0] = var; fo[1] = mn; fo[2] = mx; fo[3] = ent; fo[4] = lvar;
        f5[0] = var; f5[1] = mn; f5[2] = mx; f5[3] = ent; f5[4] = lvar;
    }
    __syncthreads();

    // tiny MLP
    if (tid < 64) {
        float aa = b1[tid];
        #pragma unroll
        for (int k = 0; k < 5; ++k) aa += W1[tid * 5 + k] * f5[k];
        h1[tid] = fmaxf(aa, 0.f);
    }
    __syncthreads();
    if (tid < 64) {
        float a2 = b2[tid];
        #pragma unroll
        for (int k = 0; k < 64; ++k) a2 += W2[tid * 64 + k] * h1[k];
        h2[tid] = fmaxf(a2, 0.f);
    }
    __syncthreads();
    if (tid < 3) {
        float a3 = b3[tid];
        #pragma unroll
        for (int k = 0; k < 64; ++k) a3 += W3[tid * 64 + k] * h2[k];
        lg[tid] = a3;
    }
    __syncthreads();
    if (tid == 0) {
        float m = fmaxf(lg[0], fmaxf(lg[1], lg[2]));
        float e0 = expf(lg[0] - m), e1 = expf(lg[1] - m), e2 = expf(lg[2] - m);
        float inv = 1.f / (e0 + e1 + e2);
        float p0 = e0 * inv, p1 = e1 * inv, p2 = e2 * inv;
        out[16 + ib * 3 + 0] = p0;
        out[16 + ib * 3 + 1] = p1;
        out[16 + ib * 3 + 2] = p2;
        int cid = 0; float bm = p0;
        if (p1 > bm) { bm = p1; cid = 1; }
        if (p2 > bm) { bm = p2; cid = 2; }
        out[ib] = (float)cid;
    }
}

extern "C" void kernel_launch(void* const* d_in, const int* in_sizes, int n_in,
                              void* d_out, int out_size, void* d_ws, size_t ws_size,
                              hipStream_t stream) {
    const float* img = (const float*)d_in[0];
    const float* W1  = (const float*)d_in[1];
    const float* b1  = (const float*)d_in[2];
    const float* W2  = (const float*)d_in[3];
    const float* b2  = (const float*)d_in[4];
    const float* W3  = (const float*)d_in[5];
    const float* b3  = (const float*)d_in[6];
    float* out = (float*)d_out;

    char* ws = (char*)d_ws;
    uint2*    mmp   = (uint2*)ws;                 // 1024 uint2     (8 KB)
    double*   mom   = (double*)(ws + 8192);       // 1024*4 double  (32 KB)
    unsigned* bhist = (unsigned*)(ws + 40960);    // 1024*256 uint  (1 MB)

    void* kargs[] = { (void*)&img, (void*)&mmp, (void*)&mom, (void*)&bhist };
    hipLaunchCooperativeKernel((const void*)k_fused12, dim3(NBLK), dim3(256),
                               kargs, 0, stream);
    k_final<<<IMG_B, 256, 0, stream>>>(bhist, mom, mmp,
                                       W1, b1, W2, b2, W3, b3, out);
}

// Round 4
// 246.479 us; speedup vs baseline: 1.1769x; 1.1769x over previous
//
#include <hip/hip_runtime.h>
#include <cfloat>
#include <math.h>

#define IMG_B 16
#define IMG_H 1024
#define IMG_W 1280
#define NPIX (IMG_H * IMG_W)          // 1,310,720
#define BINS 256
#define SLICES 64                     // slices per image (16 rows each)
#define NBLK (IMG_B * SLICES)         // 1024
#define F4_PER_SLICE (16 * IMG_W / 4) // 5120

// ---------- helpers ----------
__device__ __forceinline__ unsigned encf(float f) {
    unsigned u = __float_as_uint(f);
    return (u >> 31) ? ~u : (u | 0x80000000u);
}
__device__ __forceinline__ float decf(unsigned u) {
    unsigned b = (u & 0x80000000u) ? (u & 0x7fffffffu) : ~u;
    return __uint_as_float(b);
}
// agent-scope (device) coherent accesses — write-through / L2-bypassing, so
// cross-XCD readers see them without relying on fence-driven L2 writeback.
__device__ __forceinline__ void st_u32(unsigned* p, unsigned v) {
    __hip_atomic_store(p, v, __ATOMIC_RELAXED, __HIP_MEMORY_SCOPE_AGENT);
}
__device__ __forceinline__ unsigned ld_u32(const unsigned* p) {
    return __hip_atomic_load(p, __ATOMIC_RELAXED, __HIP_MEMORY_SCOPE_AGENT);
}
__device__ __forceinline__ void st_f64(double* p, double v) {
    __hip_atomic_store((unsigned long long*)p, (unsigned long long)__double_as_longlong(v),
                       __ATOMIC_RELAXED, __HIP_MEMORY_SCOPE_AGENT);
}
__device__ __forceinline__ double ld_f64(const double* p) {
    return __longlong_as_double((long long)__hip_atomic_load(
        (const unsigned long long*)p, __ATOMIC_RELAXED, __HIP_MEMORY_SCOPE_AGENT));
}

// ws layout (bytes):
//   mmp   : uint2[1024]      @ 0       per-slice (min,max) encoded       8 KB
//   mom   : double[1024*4]   @ 8192    per-slice S,S2,LS,LS2            32 KB
//   bhist : uint[1024*256]   @ 40960   per-slice fixed-point histogram   1 MB
//   cnt   : u32[16]          @ 1089536 per-image arrival counters
// mmp/mom/bhist fully overwritten; cnt zeroed by k_minmax blocks 0..15.

// ========== Kernel 1: per-slice min/max (pure streaming, BW-bound) =========
__global__ __launch_bounds__(256) void k_minmax(const float* __restrict__ img,
                                                uint2* __restrict__ mmp,
                                                unsigned* __restrict__ cnt) {
    const int blk = blockIdx.x;
    const int tid = threadIdx.x;
    const int lane = tid & 63, wv = tid >> 6;

    if (blk < IMG_B && tid == 0) cnt[blk] = 0u;   // visible at kernel boundary

    const float4* p = (const float4*)img + (size_t)blk * F4_PER_SLICE;
    float fmn = FLT_MAX, fmx = -FLT_MAX;
    #pragma unroll 4
    for (int k = 0; k < 20; ++k) {               // 20*256 = 5120 float4
        float4 v = p[tid + k * 256];
        fmn = fminf(fmn, fminf(fminf(v.x, v.y), fminf(v.z, v.w)));
        fmx = fmaxf(fmx, fmaxf(fmaxf(v.x, v.y), fmaxf(v.z, v.w)));
    }
    for (int o = 32; o; o >>= 1) {
        fmn = fminf(fmn, __shfl_down(fmn, (unsigned)o, 64));
        fmx = fmaxf(fmx, __shfl_down(fmx, (unsigned)o, 64));
    }
    __shared__ float rmn[4], rmx[4];
    if (lane == 0) { rmn[wv] = fmn; rmx[wv] = fmx; }
    __syncthreads();
    if (tid == 0) {
        float mn = fminf(fminf(rmn[0], rmn[1]), fminf(rmn[2], rmn[3]));
        float mx = fmaxf(fmaxf(rmx[0], rmx[1]), fmaxf(rmx[2], rmx[3]));
        mmp[blk] = make_uint2(encf(mn), encf(mx));
    }
}

// ====== Kernel 2: moments + Laplacian + histogram + last-block finisher =====
// Data handoff to the finisher uses UNCONTENDED agent-scope atomic stores
// (unique addresses), not contended RMWs (round-1's 105us failure mode), and
// the finisher never waits — the last arriving block of each image runs it.
__global__ __launch_bounds__(256) void k_main(
    const float* __restrict__ img, const uint2* __restrict__ mmp,
    double* __restrict__ mom, unsigned* __restrict__ bhist,
    unsigned* __restrict__ cnt,
    const float* __restrict__ W1, const float* __restrict__ b1,
    const float* __restrict__ W2, const float* __restrict__ b2,
    const float* __restrict__ W3, const float* __restrict__ b3,
    float* __restrict__ out)
{
    const int blk = blockIdx.x;
    const int tid = threadIdx.x;
    const int b   = blk >> 6;           // image
    const int sl  = blk & 63;           // slice (16 rows)
    const int lane = tid & 63, wv = tid >> 6;

    __shared__ unsigned long long lh64[BINS + 1];
    __shared__ float sh_ab[2];
    __shared__ float swred[4][4];
    __shared__ unsigned slast;

    // image min/max from the 64 slice partials -> normalization coefficients
    if (tid < 64) {
        uint2 e = mmp[b * 64 + tid];
        unsigned emn = e.x, emx = e.y;
        for (int o = 32; o; o >>= 1) {
            emn = min(emn, (unsigned)__shfl_down(emn, (unsigned)o, 64));
            emx = max(emx, (unsigned)__shfl_down(emx, (unsigned)o, 64));
        }
        if (tid == 0) {
            float fmn = decf(emn), fmx = decf(emx);
            float rng = fmx - fmn;
            if (rng == 0.f) rng = 1.f;
            float a = 256.f / rng;                 // pp = v*a + bb
            float bb = -fmn * a - 0.5f;
            sh_ab[0] = a; sh_ab[1] = bb;
        }
    }
    lh64[tid] = 0ull;
    if (tid == 0) lh64[BINS] = 0ull;
    __syncthreads();

    const float a = sh_ab[0], bb = sh_ab[1];
    const float* base = img + (size_t)b * NPIX;
    const int r0 = sl * 16;

    float fs = 0.f, fs2 = 0.f, fls = 0.f, fls2 = 0.f;

    #pragma unroll 2
    for (int k = 0; k < 20; ++k) {               // 20*256 = 5120 float4
        int i   = tid + k * 256;
        int ri  = i / 320;                        // row within slice
        int c   = i - ri * 320;                   // float4 col 0..319
        int r   = r0 + ri;
        const float* rowf = base + (size_t)r * IMG_W;
        float4 m = ((const float4*)rowf)[c];
        float4 up = make_float4(0.f, 0.f, 0.f, 0.f);
        float4 dn = make_float4(0.f, 0.f, 0.f, 0.f);
        if (r > 0)          up = ((const float4*)(rowf - IMG_W))[c];
        if (r < IMG_H - 1)  dn = ((const float4*)(rowf + IMG_W))[c];
        float lft = (c > 0)   ? rowf[4 * c - 1] : 0.f;
        float rgt = (c < 319) ? rowf[4 * c + 4] : 0.f;

        // moments (identical op order to the verified kernel)
        fs  += (m.x + m.y) + (m.z + m.w);
        fs2 += (m.x * m.x + m.y * m.y) + (m.z * m.z + m.w * m.w);

        // Laplacian moments
        float l0 = up.x + dn.x + lft + m.y - 4.f * m.x;
        float l1 = up.y + dn.y + m.x + m.z - 4.f * m.y;
        float l2 = up.z + dn.z + m.y + m.w - 4.f * m.z;
        float l3 = up.w + dn.w + m.z + rgt - 4.f * m.w;
        fls  += (l0 + l1) + (l2 + l3);
        fls2 += (l0 * l0 + l1 * l1) + (l2 * l2 + l3 * l3);

        // packed-u64 soft histogram (1 DS atomic / pixel, identical math)
        #pragma unroll
        for (int j = 0; j < 4; ++j) {
            float vv = (j == 0) ? m.x : (j == 1) ? m.y : (j == 2) ? m.z : m.w;
            float pp = fminf(fmaxf(vv * a + bb, -0.5f), 255.5f);
            float fi = floorf(pp);
            int   i0 = (int)fi;                   // -1 .. 255
            unsigned w1q = (unsigned)((pp - fi) * 65536.f + 0.5f);
            atomicAdd(&lh64[i0 + 1], 0x100000000ull + (unsigned long long)w1q);
        }
    }

    // register-only cross-lane reduction of moments
    for (int o = 32; o; o >>= 1) {
        fs   += __shfl_down(fs,   (unsigned)o, 64);
        fs2  += __shfl_down(fs2,  (unsigned)o, 64);
        fls  += __shfl_down(fls,  (unsigned)o, 64);
        fls2 += __shfl_down(fls2, (unsigned)o, 64);
    }
    if (lane == 0) {
        swred[0][wv] = fs;  swred[1][wv] = fs2;
        swred[2][wv] = fls; swred[3][wv] = fls2;
    }
    __syncthreads();   // all waves' DS atomics + swred stores complete

    if (tid == 0) {
        double S   = (double)swred[0][0] + (double)swred[0][1] + (double)swred[0][2] + (double)swred[0][3];
        double S2  = (double)swred[1][0] + (double)swred[1][1] + (double)swred[1][2] + (double)swred[1][3];
        double LS  = (double)swred[2][0] + (double)swred[2][1] + (double)swred[2][2] + (double)swred[2][3];
        double LS2 = (double)swred[3][0] + (double)swred[3][1] + (double)swred[3][2] + (double)swred[3][3];
        st_f64(&mom[blk * 4 + 0], S);  st_f64(&mom[blk * 4 + 1], S2);
        st_f64(&mom[blk * 4 + 2], LS); st_f64(&mom[blk * 4 + 3], LS2);
    }

    // per-slice fixed-point histogram writeback (unique addresses, coherent)
    {
        unsigned long long a0 = lh64[tid];
        unsigned long long a1 = lh64[tid + 1];
        unsigned long long h  = ((a1 >> 32) << 16) - (a1 & 0xffffffffull) + (a0 & 0xffffffffull);
        st_u32(&bhist[blk * BINS + tid], (unsigned)h);   // < 2^31
    }

    // arrival: release our stores, bump this image's counter; last block finishes
    __threadfence();
    __syncthreads();
    if (tid == 0)
        slast = (__hip_atomic_fetch_add(&cnt[b], 1u, __ATOMIC_ACQ_REL,
                                        __HIP_MEMORY_SCOPE_AGENT) == 63u) ? 1u : 0u;
    __syncthreads();
    if (!slast) return;
    __threadfence();   // acquire side

    // ----------------- finisher (verified k_final body, image b) -------------
    const int ib = b;

    __shared__ double dred[4];
    __shared__ float  fred[4];
    __shared__ double smom[4];
    __shared__ unsigned smm2[2];
    __shared__ unsigned sgm[4];
    __shared__ float f5[5], h1[64], h2[64], lg[3];

    // per-bin total over 64 slice histograms (exact in double)
    double h = 0.0;
    for (int s = 0; s < 64; ++s)
        h += (double)ld_u32(&bhist[(ib * 64 + s) * BINS + tid]);

    double tot = h;
    for (int o = 32; o; o >>= 1) tot += __shfl_down(tot, (unsigned)o, 64);
    if (lane == 0) dred[wv] = tot;
    __syncthreads();
    tot = dred[0] + dred[1] + dred[2] + dred[3];

    double hv = h * (1.0 / 65536.0);
    double tv = tot * (1.0 / 65536.0);
    float hn = (float)(hv / (tv + 1e-10));
    float ce = hn * log2f(hn + 1e-10f);
    for (int o = 32; o; o >>= 1) ce += __shfl_down(ce, (unsigned)o, 64);
    if (lane == 0) fred[wv] = ce;

    if (tid < 64) {   // moments + image min/max
        double q0 = ld_f64(&mom[(ib * 64 + tid) * 4 + 0]);
        double q1 = ld_f64(&mom[(ib * 64 + tid) * 4 + 1]);
        double q2 = ld_f64(&mom[(ib * 64 + tid) * 4 + 2]);
        double q3 = ld_f64(&mom[(ib * 64 + tid) * 4 + 3]);
        uint2 e = mmp[ib * 64 + tid];
        unsigned emn = e.x, emx = e.y;
        for (int o = 32; o; o >>= 1) {
            q0 += __shfl_down(q0, (unsigned)o, 64);
            q1 += __shfl_down(q1, (unsigned)o, 64);
            q2 += __shfl_down(q2, (unsigned)o, 64);
            q3 += __shfl_down(q3, (unsigned)o, 64);
            emn = min(emn, (unsigned)__shfl_down(emn, (unsigned)o, 64));
            emx = max(emx, (unsigned)__shfl_down(emx, (unsigned)o, 64));
        }
        if (tid == 0) {
            smom[0] = q0; smom[1] = q1; smom[2] = q2; smom[3] = q3;
            smm2[0] = emn; smm2[1] = emx;
        }
    }
    {   // global max over all 1024 slice maxima (scale decision)
        unsigned g = max(max(mmp[tid].y, mmp[256 + tid].y),
                         max(mmp[512 + tid].y, mmp[768 + tid].y));
        for (int o = 32; o; o >>= 1)
            g = max(g, (unsigned)__shfl_down(g, (unsigned)o, 64));
        if (lane == 0) sgm[wv] = g;
    }
    __syncthreads();

    if (tid == 0) {
        float ent = -(fred[0] + fred[1] + fred[2] + fred[3]) / 8.f;  // /log2(256)
        float gmax = decf(max(max(sgm[0], sgm[1]), max(sgm[2], sgm[3])));
        float sc = (gmax > 1.f) ? (1.f / 16383.f) : 1.f;
        double N = (double)NPIX;
        double S = smom[0], S2 = smom[1], LS = smom[2], LS2 = smom[3];
        double sc2 = (double)sc * (double)sc;
        float var  = (float)((S2  - S  * S  / N) / (N - 1.0) * sc2);
        float lvar = (float)((LS2 - LS * LS / N) / (N - 1.0) * sc2);
        float mn = decf(smm2[0]) * sc;
        float mx = decf(smm2[1]) * sc;
        float* fo = out + 64 + ib * 5;
        fo[0] = var; fo[1] = mn; fo[2] = mx; fo[3] = ent; fo[4] = lvar;
        f5[0] = var; f5[1] = mn; f5[2] = mx; f5[3] = ent; f5[4] = lvar;
    }
    __syncthreads();

    // tiny MLP
    if (tid < 64) {
        float aa = b1[tid];
        #pragma unroll
        for (int k = 0; k < 5; ++k) aa += W1[tid * 5 + k] * f5[k];
        h1[tid] = fmaxf(aa, 0.f);
    }
    __syncthreads();
    if (tid < 64) {
        float a2 = b2[tid];
        #pragma unroll
        for (int k = 0; k < 64; ++k) a2 += W2[tid * 64 + k] * h1[k];
        h2[tid] = fmaxf(a2, 0.f);
    }
    __syncthreads();
    if (tid < 3) {
        float a3 = b3[tid];
        #pragma unroll
        for (int k = 0; k < 64; ++k) a3 += W3[tid * 64 + k] * h2[k];
        lg[tid] = a3;
    }
    __syncthreads();
    if (tid == 0) {
        float m = fmaxf(lg[0], fmaxf(lg[1], lg[2]));
        float e0 = expf(lg[0] - m), e1 = expf(lg[1] - m), e2 = expf(lg[2] - m);
        float inv = 1.f / (e0 + e1 + e2);
        float p0 = e0 * inv, p1 = e1 * inv, p2 = e2 * inv;
        out[16 + ib * 3 + 0] = p0;
        out[16 + ib * 3 + 1] = p1;
        out[16 + ib * 3 + 2] = p2;
        int cid = 0; float bm = p0;
        if (p1 > bm) { bm = p1; cid = 1; }
        if (p2 > bm) { bm = p2; cid = 2; }
        out[ib] = (float)cid;
    }
}

extern "C" void kernel_launch(void* const* d_in, const int* in_sizes, int n_in,
                              void* d_out, int out_size, void* d_ws, size_t ws_size,
                              hipStream_t stream) {
    const float* img = (const float*)d_in[0];
    const float* W1  = (const float*)d_in[1];
    const float* b1  = (const float*)d_in[2];
    const float* W2  = (const float*)d_in[3];
    const float* b2  = (const float*)d_in[4];
    const float* W3  = (const float*)d_in[5];
    const float* b3  = (const float*)d_in[6];
    float* out = (float*)d_out;

    char* ws = (char*)d_ws;
    uint2*    mmp   = (uint2*)ws;                    // 1024 uint2     (8 KB)
    double*   mom   = (double*)(ws + 8192);          // 1024*4 double  (32 KB)
    unsigned* bhist = (unsigned*)(ws + 40960);       // 1024*256 uint  (1 MB)
    unsigned* cnt   = (unsigned*)(ws + 40960 + (size_t)NBLK * BINS * 4); // 64 B

    k_minmax<<<NBLK, 256, 0, stream>>>(img, mmp, cnt);
    k_main  <<<NBLK, 256, 0, stream>>>(img, mmp, mom, bhist, cnt,
                                       W1, b1, W2, b2, W3, b3, out);
}

// Round 5
// 158.132 us; speedup vs baseline: 1.8344x; 1.5587x over previous
//
#include <hip/hip_runtime.h>
#include <cfloat>
#include <math.h>

#define IMG_B 16
#define IMG_H 1024
#define IMG_W 1280
#define NPIX (IMG_H * IMG_W)          // 1,310,720
#define BINS 256
#define SLICES 64                     // k_pre slices per image (16 rows)
#define NBLK (IMG_B * SLICES)         // 1024
#define HSLICES 128                   // k_hist slices per image (8 rows)
#define HBLK (IMG_B * HSLICES)        // 2048
#define F4_PER_SLICE (16 * IMG_W / 4) // 5120
#define F4_PER_HSLICE (8 * IMG_W / 4) // 2560

// ---------- helpers ----------
__device__ __forceinline__ unsigned encf(float f) {
    unsigned u = __float_as_uint(f);
    return (u >> 31) ? ~u : (u | 0x80000000u);
}
__device__ __forceinline__ float decf(unsigned u) {
    unsigned b = (u & 0x80000000u) ? (u & 0x7fffffffu) : ~u;
    return __uint_as_float(b);
}

// ws layout (bytes):
//   mmp   : uint2[1024]      @ 0       per-slice (min,max) encoded       8 KB
//   mom   : double[1024*4]   @ 8192    per-slice S,S2,LS,LS2            32 KB
//   bhist : uint[2048*256]   @ 40960   per-8-row-slice fixed-point hist  2 MB
// All fully overwritten every call -> no init kernel needed.
// NOTE (journal): all intra-kernel grid-handoff schemes measured 2x+ worse
// (coop grid.sync +100us; global RMW +95us; agent-store+fence +95us). The
// kernel boundary (~2us) is the cheapest grid barrier on this part.

// ========== Kernel 1: min/max + moments + Laplacian (verified body) ========
__global__ __launch_bounds__(256) void k_pre(const float* __restrict__ img,
                                             uint2* __restrict__ mmp,
                                             double* __restrict__ mom) {
    const int blk = blockIdx.x;
    const int tid = threadIdx.x;
    const int b   = blk >> 6;           // image
    const int sl  = blk & 63;           // slice (16 rows)
    const int lane = tid & 63, wv = tid >> 6;

    const float* base = img + (size_t)b * NPIX;
    const int r0 = sl * 16;

    float fs = 0.f, fs2 = 0.f, fls = 0.f, fls2 = 0.f;
    float fmn = FLT_MAX, fmx = -FLT_MAX;

    #pragma unroll 2
    for (int k = 0; k < 20; ++k) {               // 20*256 = 5120 float4
        int i   = tid + k * 256;
        int ri  = i / 320;                        // row within slice
        int c   = i - ri * 320;                   // float4 col 0..319
        int r   = r0 + ri;
        const float* rowf = base + (size_t)r * IMG_W;
        float4 m = ((const float4*)rowf)[c];
        float4 up = make_float4(0.f, 0.f, 0.f, 0.f);
        float4 dn = make_float4(0.f, 0.f, 0.f, 0.f);
        if (r > 0)          up = ((const float4*)(rowf - IMG_W))[c];
        if (r < IMG_H - 1)  dn = ((const float4*)(rowf + IMG_W))[c];
        float lft = (c > 0)   ? rowf[4 * c - 1] : 0.f;
        float rgt = (c < 319) ? rowf[4 * c + 4] : 0.f;

        fs  += (m.x + m.y) + (m.z + m.w);
        fs2 += (m.x * m.x + m.y * m.y) + (m.z * m.z + m.w * m.w);
        fmn = fminf(fmn, fminf(fminf(m.x, m.y), fminf(m.z, m.w)));
        fmx = fmaxf(fmx, fmaxf(fmaxf(m.x, m.y), fmaxf(m.z, m.w)));

        float l0 = up.x + dn.x + lft + m.y - 4.f * m.x;
        float l1 = up.y + dn.y + m.x + m.z - 4.f * m.y;
        float l2 = up.z + dn.z + m.y + m.w - 4.f * m.z;
        float l3 = up.w + dn.w + m.z + rgt - 4.f * m.w;
        fls  += (l0 + l1) + (l2 + l3);
        fls2 += (l0 * l0 + l1 * l1) + (l2 * l2 + l3 * l3);
    }

    for (int o = 32; o; o >>= 1) {
        fs   += __shfl_down(fs,   (unsigned)o, 64);
        fs2  += __shfl_down(fs2,  (unsigned)o, 64);
        fls  += __shfl_down(fls,  (unsigned)o, 64);
        fls2 += __shfl_down(fls2, (unsigned)o, 64);
        fmn = fminf(fmn, __shfl_down(fmn, (unsigned)o, 64));
        fmx = fmaxf(fmx, __shfl_down(fmx, (unsigned)o, 64));
    }
    __shared__ float swred[4][4];
    __shared__ float rmn[4], rmx[4];
    if (lane == 0) {
        swred[0][wv] = fs;  swred[1][wv] = fs2;
        swred[2][wv] = fls; swred[3][wv] = fls2;
        rmn[wv] = fmn; rmx[wv] = fmx;
    }
    __syncthreads();
    if (tid == 0) {
        double S   = (double)swred[0][0] + (double)swred[0][1] + (double)swred[0][2] + (double)swred[0][3];
        double S2  = (double)swred[1][0] + (double)swred[1][1] + (double)swred[1][2] + (double)swred[1][3];
        double LS  = (double)swred[2][0] + (double)swred[2][1] + (double)swred[2][2] + (double)swred[2][3];
        double LS2 = (double)swred[3][0] + (double)swred[3][1] + (double)swred[3][2] + (double)swred[3][3];
        mom[blk * 4 + 0] = S;  mom[blk * 4 + 1] = S2;
        mom[blk * 4 + 2] = LS; mom[blk * 4 + 3] = LS2;
        float mn = fminf(fminf(rmn[0], rmn[1]), fminf(rmn[2], rmn[3]));
        float mx = fmaxf(fmaxf(rmx[0], rmx[1]), fmaxf(rmx[2], rmx[3]));
        mmp[blk] = make_uint2(encf(mn), encf(mx));
    }
}

// ========== Kernel 2: packed-u64 soft histogram, 8-row slices ==============
// 2048 blocks -> 8 blocks/CU (32/32 waves) vs the old 4: the DS-atomic pipe
// is latency/occupancy limited at 29% (HBM 5%, VALU 11%), so doubling the
// co-resident wave count doubles the independent atomic streams.
// Histogram totals are integer sums -> partition-independent, bit-identical.
__global__ __launch_bounds__(256, 8) void k_hist(const float* __restrict__ img,
                                                 const uint2* __restrict__ mmp,
                                                 unsigned* __restrict__ bhist) {
    const int blk = blockIdx.x;
    const int tid = threadIdx.x;
    const int b   = blk >> 7;           // image (128 slices each)

    __shared__ unsigned long long lh64[BINS + 1];
    __shared__ float sh_ab[2];

    // image min/max from the 64 k_pre slice partials
    if (tid < 64) {
        uint2 e = mmp[b * 64 + tid];
        unsigned emn = e.x, emx = e.y;
        for (int o = 32; o; o >>= 1) {
            emn = min(emn, (unsigned)__shfl_down(emn, (unsigned)o, 64));
            emx = max(emx, (unsigned)__shfl_down(emx, (unsigned)o, 64));
        }
        if (tid == 0) {
            float fmn = decf(emn), fmx = decf(emx);
            float rng = fmx - fmn;
            if (rng == 0.f) rng = 1.f;
            float a = 256.f / rng;                 // pp = v*a + bb
            float bb = -fmn * a - 0.5f;
            sh_ab[0] = a; sh_ab[1] = bb;
        }
    }
    lh64[tid] = 0ull;
    if (tid == 0) lh64[BINS] = 0ull;
    __syncthreads();

    const float a = sh_ab[0], bb = sh_ab[1];

    const float4* p = (const float4*)img + (size_t)blk * F4_PER_HSLICE;
    #pragma unroll 2
    for (int k = 0; k < 10; ++k) {               // 10*256 = 2560 float4
        float4 v = p[tid + k * 256];
        #pragma unroll
        for (int j = 0; j < 4; ++j) {
            float vv = (j == 0) ? v.x : (j == 1) ? v.y : (j == 2) ? v.z : v.w;
            float pp = fminf(fmaxf(vv * a + bb, -0.5f), 255.5f);
            float fi = floorf(pp);
            int   i0 = (int)fi;                   // -1 .. 255
            unsigned w1q = (unsigned)((pp - fi) * 65536.f + 0.5f);
            atomicAdd(&lh64[i0 + 1], 0x100000000ull + (unsigned long long)w1q);
        }
    }
    __syncthreads();

    unsigned long long a0 = lh64[tid];
    unsigned long long a1 = lh64[tid + 1];
    unsigned long long h  = ((a1 >> 32) << 16) - (a1 & 0xffffffffull) + (a0 & 0xffffffffull);
    bhist[blk * BINS + tid] = (unsigned)h;       // <= 65536*10240 < 2^31
}

// ===================== Kernel 3: reduce + feats + MLP ======================
// 1024 threads: 4 partial-sum groups of 32 slices each (integer values summed
// in double -> exact in any order), then the verified 256-thread body.
__global__ __launch_bounds__(1024) void k_final(
    const unsigned* __restrict__ bhist, const double* __restrict__ mom,
    const uint2* __restrict__ mmp,
    const float* __restrict__ W1, const float* __restrict__ b1,
    const float* __restrict__ W2, const float* __restrict__ b2,
    const float* __restrict__ W3, const float* __restrict__ b3,
    float* __restrict__ out)
{
    const int ib  = blockIdx.x;    // image
    const int tid = threadIdx.x;   // 0..1023
    const int bin = tid & 255;
    const int part = tid >> 8;     // 0..3
    const int lane = tid & 63, wv = tid >> 6;

    __shared__ double hp[4][BINS];
    __shared__ double dred[4];
    __shared__ float  fred[4];
    __shared__ double smom[4];
    __shared__ unsigned smm2[2];
    __shared__ unsigned sgm[4];
    __shared__ float f5[5], h1[64], h2[64], lg[3];

    // 4-way split per-bin total over the 128 slice histograms (exact)
    {
        double hs = 0.0;
        const unsigned* q = bhist + ((size_t)ib * HSLICES + part * 32) * BINS + bin;
        #pragma unroll 4
        for (int s = 0; s < 32; ++s) hs += (double)q[s * BINS];
        hp[part][bin] = hs;
    }
    __syncthreads();

    double h = 0.0;
    if (tid < 256) {
        h = (hp[0][bin] + hp[1][bin]) + (hp[2][bin] + hp[3][bin]);  // exact ints
        double tot = h;
        for (int o = 32; o; o >>= 1) tot += __shfl_down(tot, (unsigned)o, 64);
        if (lane == 0) dred[wv] = tot;
    }
    __syncthreads();
    if (tid < 256) {
        double tot = dred[0] + dred[1] + dred[2] + dred[3];
        double hv = h * (1.0 / 65536.0);
        double tv = tot * (1.0 / 65536.0);
        float hn = (float)(hv / (tv + 1e-10));
        float ce = hn * log2f(hn + 1e-10f);
        for (int o = 32; o; o >>= 1) ce += __shfl_down(ce, (unsigned)o, 64);
        if (lane == 0) fred[wv] = ce;
    }

    if (tid < 64) {   // moments + image min/max (verified body)
        double q0 = mom[(ib * 64 + tid) * 4 + 0];
        double q1 = mom[(ib * 64 + tid) * 4 + 1];
        double q2 = mom[(ib * 64 + tid) * 4 + 2];
        double q3 = mom[(ib * 64 + tid) * 4 + 3];
        uint2 e = mmp[ib * 64 + tid];
        unsigned emn = e.x, emx = e.y;
        for (int o = 32; o; o >>= 1) {
            q0 += __shfl_down(q0, (unsigned)o, 64);
            q1 += __shfl_down(q1, (unsigned)o, 64);
            q2 += __shfl_down(q2, (unsigned)o, 64);
            q3 += __shfl_down(q3, (unsigned)o, 64);
            emn = min(emn, (unsigned)__shfl_down(emn, (unsigned)o, 64));
            emx = max(emx, (unsigned)__shfl_down(emx, (unsigned)o, 64));
        }
        if (tid == 0) {
            smom[0] = q0; smom[1] = q1; smom[2] = q2; smom[3] = q3;
            smm2[0] = emn; smm2[1] = emx;
        }
    }
    if (tid < 256) {   // global max over all 1024 slice maxima (scale decision)
        unsigned g = max(max(mmp[tid].y, mmp[256 + tid].y),
                         max(mmp[512 + tid].y, mmp[768 + tid].y));
        for (int o = 32; o; o >>= 1)
            g = max(g, (unsigned)__shfl_down(g, (unsigned)o, 64));
        if (lane == 0) sgm[wv] = g;
    }
    __syncthreads();

    if (tid == 0) {
        float ent = -(fred[0] + fred[1] + fred[2] + fred[3]) / 8.f;  // /log2(256)
        float gmax = decf(max(max(sgm[0], sgm[1]), max(sgm[2], sgm[3])));
        float sc = (gmax > 1.f) ? (1.f / 16383.f) : 1.f;
        double N = (double)NPIX;
        double S = smom[0], S2 = smom[1], LS = smom[2], LS2 = smom[3];
        double sc2 = (double)sc * (double)sc;
        float var  = (float)((S2  - S  * S  / N) / (N - 1.0) * sc2);
        float lvar = (float)((LS2 - LS * LS / N) / (N - 1.0) * sc2);
        float mn = decf(smm2[0]) * sc;
        float mx = decf(smm2[1]) * sc;
        float* fo = out + 64 + ib * 5;
        fo[0] = var; fo[1] = mn; fo[2] = mx; fo[3] = ent; fo[4] = lvar;
        f5[0] = var; f5[1] = mn; f5[2] = mx; f5[3] = ent; f5[4] = lvar;
    }
    __syncthreads();

    // tiny MLP
    if (tid < 64) {
        float aa = b1[tid];
        #pragma unroll
        for (int k = 0; k < 5; ++k) aa += W1[tid * 5 + k] * f5[k];
        h1[tid] = fmaxf(aa, 0.f);
    }
    __syncthreads();
    if (tid < 64) {
        float a2 = b2[tid];
        #pragma unroll
        for (int k = 0; k < 64; ++k) a2 += W2[tid * 64 + k] * h1[k];
        h2[tid] = fmaxf(a2, 0.f);
    }
    __syncthreads();
    if (tid < 3) {
        float a3 = b3[tid];
        #pragma unroll
        for (int k = 0; k < 64; ++k) a3 += W3[tid * 64 + k] * h2[k];
        lg[tid] = a3;
    }
    __syncthreads();
    if (tid == 0) {
        float m = fmaxf(lg[0], fmaxf(lg[1], lg[2]));
        float e0 = expf(lg[0] - m), e1 = expf(lg[1] - m), e2 = expf(lg[2] - m);
        float inv = 1.f / (e0 + e1 + e2);
        float p0 = e0 * inv, p1 = e1 * inv, p2 = e2 * inv;
        out[16 + ib * 3 + 0] = p0;
        out[16 + ib * 3 + 1] = p1;
        out[16 + ib * 3 + 2] = p2;
        int cid = 0; float bm = p0;
        if (p1 > bm) { bm = p1; cid = 1; }
        if (p2 > bm) { bm = p2; cid = 2; }
        out[ib] = (float)cid;
    }
}

extern "C" void kernel_launch(void* const* d_in, const int* in_sizes, int n_in,
                              void* d_out, int out_size, void* d_ws, size_t ws_size,
                              hipStream_t stream) {
    const float* img = (const float*)d_in[0];
    const float* W1  = (const float*)d_in[1];
    const float* b1  = (const float*)d_in[2];
    const float* W2  = (const float*)d_in[3];
    const float* b2  = (const float*)d_in[4];
    const float* W3  = (const float*)d_in[5];
    const float* b3  = (const float*)d_in[6];
    float* out = (float*)d_out;

    char* ws = (char*)d_ws;
    uint2*    mmp   = (uint2*)ws;                 // 1024 uint2     (8 KB)
    double*   mom   = (double*)(ws + 8192);       // 1024*4 double  (32 KB)
    unsigned* bhist = (unsigned*)(ws + 40960);    // 2048*256 uint  (2 MB)

    k_pre  <<<NBLK, 256, 0, stream>>>(img, mmp, mom);
    k_hist <<<HBLK, 256, 0, stream>>>(img, mmp, bhist);
    k_final<<<IMG_B, 1024, 0, stream>>>(bhist, mom, mmp,
                                        W1, b1, W2, b2, W3, b3, out);
}

// Round 6
// 155.697 us; speedup vs baseline: 1.8631x; 1.0156x over previous
//
#include <hip/hip_runtime.h>
#include <cfloat>
#include <math.h>

#define IMG_B 16
#define IMG_H 1024
#define IMG_W 1280
#define NPIX (IMG_H * IMG_W)          // 1,310,720
#define BINS 256
#define SLICES 64                     // slices per image (16 rows each)
#define NBLK (IMG_B * SLICES)         // 1024
#define F4_PER_SLICE (16 * IMG_W / 4) // 5120

// SESSION JOURNAL (measured, MI355X):
//  - Timed window includes 2x ~51.5us harness workspace-poison fills at
//    81-83% HBM peak (untouchable, ~103us of every result).
//  - Controllable portion ~53us: R0(157.7)/R2(156.2)/R5(158.1) are three
//    structurally distinct decompositions within a 2us band -> floor =
//    one cold 84MB read + one L3-warm reread w/ DS-atomic histogram +
//    3 launches. This file is R2, the best verified (156.24us).
//  - Intra-kernel grid handoff is NEVER worth it on this part:
//    coop grid.sync +100us (R3), contended global u64 RMW +95us (R1),
//    uncontended agent-scope stores + per-block threadfence +95us (R4).
//    The kernel boundary (~2us) IS the cheap grid barrier.

// ---------- helpers ----------
__device__ __forceinline__ unsigned encf(float f) {
    unsigned u = __float_as_uint(f);
    return (u >> 31) ? ~u : (u | 0x80000000u);
}
__device__ __forceinline__ float decf(unsigned u) {
    unsigned b = (u & 0x80000000u) ? (u & 0x7fffffffu) : ~u;
    return __uint_as_float(b);
}

// ws layout (bytes):
//   mmp   : uint2[1024]      @ 0       per-slice (min,max) encoded       8 KB
//   mom   : double[1024*4]   @ 8192    per-slice S,S2,LS,LS2            32 KB
//   bhist : uint[1024*256]   @ 40960   per-slice fixed-point histogram   1 MB
// All fully overwritten every call -> no init kernel needed.

// ========== Kernel 1: per-slice min/max (pure streaming, BW-bound) =========
__global__ __launch_bounds__(256) void k_minmax(const float* __restrict__ img,
                                                uint2* __restrict__ mmp) {
    const int blk = blockIdx.x;
    const int tid = threadIdx.x;
    const int lane = tid & 63, wv = tid >> 6;

    const float4* p = (const float4*)img + (size_t)blk * F4_PER_SLICE;
    float fmn = FLT_MAX, fmx = -FLT_MAX;
    #pragma unroll 4
    for (int k = 0; k < 20; ++k) {               // 20*256 = 5120 float4
        float4 v = p[tid + k * 256];
        fmn = fminf(fmn, fminf(fminf(v.x, v.y), fminf(v.z, v.w)));
        fmx = fmaxf(fmx, fmaxf(fmaxf(v.x, v.y), fmaxf(v.z, v.w)));
    }
    for (int o = 32; o; o >>= 1) {
        fmn = fminf(fmn, __shfl_down(fmn, (unsigned)o, 64));
        fmx = fmaxf(fmx, __shfl_down(fmx, (unsigned)o, 64));
    }
    __shared__ float rmn[4], rmx[4];
    if (lane == 0) { rmn[wv] = fmn; rmx[wv] = fmx; }
    __syncthreads();
    if (tid == 0) {
        float mn = fminf(fminf(rmn[0], rmn[1]), fminf(rmn[2], rmn[3]));
        float mx = fmaxf(fmaxf(rmx[0], rmx[1]), fmaxf(rmx[2], rmx[3]));
        mmp[blk] = make_uint2(encf(mn), encf(mx));
    }
}

// ========== Kernel 2: fused moments + Laplacian + soft histogram ===========
// One L3-warm image read serves all three. The DS-atomic pipe (histogram) is
// the critical path; moment/Laplacian VALU work and the neighbor-row loads
// hide underneath it instead of costing a separate kernel.
__global__ __launch_bounds__(256) void k_main(const float* __restrict__ img,
                                              const uint2* __restrict__ mmp,
                                              double* __restrict__ mom,
                                              unsigned* __restrict__ bhist) {
    const int blk = blockIdx.x;
    const int tid = threadIdx.x;
    const int b   = blk >> 6;           // image
    const int sl  = blk & 63;           // slice (16 rows)
    const int lane = tid & 63, wv = tid >> 6;

    __shared__ unsigned long long lh64[BINS + 1];
    __shared__ float sh_ab[2];
    __shared__ float swred[4][4];

    // image min/max from the 64 slice partials -> normalization coefficients
    if (tid < 64) {
        uint2 e = mmp[b * 64 + tid];
        unsigned emn = e.x, emx = e.y;
        for (int o = 32; o; o >>= 1) {
            emn = min(emn, (unsigned)__shfl_down(emn, (unsigned)o, 64));
            emx = max(emx, (unsigned)__shfl_down(emx, (unsigned)o, 64));
        }
        if (tid == 0) {
            float fmn = decf(emn), fmx = decf(emx);
            float rng = fmx - fmn;
            if (rng == 0.f) rng = 1.f;
            float a = 256.f / rng;                 // pp = v*a + bb
            float bb = -fmn * a - 0.5f;
            sh_ab[0] = a; sh_ab[1] = bb;
        }
    }
    lh64[tid] = 0ull;
    if (tid == 0) lh64[BINS] = 0ull;
    __syncthreads();

    const float a = sh_ab[0], bb = sh_ab[1];
    const float* base = img + (size_t)b * NPIX;
    const int r0 = sl * 16;

    float fs = 0.f, fs2 = 0.f, fls = 0.f, fls2 = 0.f;

    #pragma unroll 2
    for (int k = 0; k < 20; ++k) {               // 20*256 = 5120 float4
        int i   = tid + k * 256;
        int ri  = i / 320;                        // row within slice
        int c   = i - ri * 320;                   // float4 col 0..319
        int r   = r0 + ri;
        const float* rowf = base + (size_t)r * IMG_W;
        float4 m = ((const float4*)rowf)[c];
        float4 up = make_float4(0.f, 0.f, 0.f, 0.f);
        float4 dn = make_float4(0.f, 0.f, 0.f, 0.f);
        if (r > 0)          up = ((const float4*)(rowf - IMG_W))[c];
        if (r < IMG_H - 1)  dn = ((const float4*)(rowf + IMG_W))[c];
        float lft = (c > 0)   ? rowf[4 * c - 1] : 0.f;
        float rgt = (c < 319) ? rowf[4 * c + 4] : 0.f;

        // moments (identical op order to the verified kernel)
        fs  += (m.x + m.y) + (m.z + m.w);
        fs2 += (m.x * m.x + m.y * m.y) + (m.z * m.z + m.w * m.w);

        // Laplacian moments
        float l0 = up.x + dn.x + lft + m.y - 4.f * m.x;
        float l1 = up.y + dn.y + m.x + m.z - 4.f * m.y;
        float l2 = up.z + dn.z + m.y + m.w - 4.f * m.z;
        float l3 = up.w + dn.w + m.z + rgt - 4.f * m.w;
        fls  += (l0 + l1) + (l2 + l3);
        fls2 += (l0 * l0 + l1 * l1) + (l2 * l2 + l3 * l3);

        // packed-u64 soft histogram (1 DS atomic / pixel, identical math)
        #pragma unroll
        for (int j = 0; j < 4; ++j) {
            float vv = (j == 0) ? m.x : (j == 1) ? m.y : (j == 2) ? m.z : m.w;
            float pp = fminf(fmaxf(vv * a + bb, -0.5f), 255.5f);
            float fi = floorf(pp);
            int   i0 = (int)fi;                   // -1 .. 255
            unsigned w1q = (unsigned)((pp - fi) * 65536.f + 0.5f);
            atomicAdd(&lh64[i0 + 1], 0x100000000ull + (unsigned long long)w1q);
        }
    }

    // register-only cross-lane reduction of moments (independent of LDS)
    for (int o = 32; o; o >>= 1) {
        fs   += __shfl_down(fs,   (unsigned)o, 64);
        fs2  += __shfl_down(fs2,  (unsigned)o, 64);
        fls  += __shfl_down(fls,  (unsigned)o, 64);
        fls2 += __shfl_down(fls2, (unsigned)o, 64);
    }
    if (lane == 0) {
        swred[0][wv] = fs;  swred[1][wv] = fs2;
        swred[2][wv] = fls; swred[3][wv] = fls2;
    }
    __syncthreads();   // all waves' atomics + swred stores complete

    if (tid == 0) {
        double S   = (double)swred[0][0] + (double)swred[0][1] + (double)swred[0][2] + (double)swred[0][3];
        double S2  = (double)swred[1][0] + (double)swred[1][1] + (double)swred[1][2] + (double)swred[1][3];
        double LS  = (double)swred[2][0] + (double)swred[2][1] + (double)swred[2][2] + (double)swred[2][3];
        double LS2 = (double)swred[3][0] + (double)swred[3][1] + (double)swred[3][2] + (double)swred[3][3];
        mom[blk * 4 + 0] = S;  mom[blk * 4 + 1] = S2;
        mom[blk * 4 + 2] = LS; mom[blk * 4 + 3] = LS2;
    }

    // per-slice fixed-point histogram writeback (contention-free)
    unsigned long long a0 = lh64[tid];
    unsigned long long a1 = lh64[tid + 1];
    unsigned long long h  = ((a1 >> 32) << 16) - (a1 & 0xffffffffull) + (a0 & 0xffffffffull);
    bhist[blk * BINS + tid] = (unsigned)h;       // < 2^31
}

// ===================== Kernel 3: reduce + feats + MLP ======================
__global__ __launch_bounds__(256) void k_final(
    const unsigned* __restrict__ bhist, const double* __restrict__ mom,
    const uint2* __restrict__ mmp,
    const float* __restrict__ W1, const float* __restrict__ b1,
    const float* __restrict__ W2, const float* __restrict__ b2,
    const float* __restrict__ W3, const float* __restrict__ b3,
    float* __restrict__ out)
{
    const int ib = blockIdx.x;    // image
    const int tid = threadIdx.x;
    const int lane = tid & 63, wv = tid >> 6;

    __shared__ double dred[4];
    __shared__ float  fred[4];
    __shared__ double smom[4];
    __shared__ unsigned smm2[2];
    __shared__ unsigned sgm[4];
    __shared__ float f5[5], h1[64], h2[64], lg[3];

    // per-bin total over 64 slice histograms (exact in double)
    double h = 0.0;
    for (int s = 0; s < 64; ++s)
        h += (double)bhist[(ib * 64 + s) * BINS + tid];

    double tot = h;
    for (int o = 32; o; o >>= 1) tot += __shfl_down(tot, (unsigned)o, 64);
    if (lane == 0) dred[wv] = tot;
    __syncthreads();
    tot = dred[0] + dred[1] + dred[2] + dred[3];

    double hv = h * (1.0 / 65536.0);
    double tv = tot * (1.0 / 65536.0);
    float hn = (float)(hv / (tv + 1e-10));
    float ce = hn * log2f(hn + 1e-10f);
    for (int o = 32; o; o >>= 1) ce += __shfl_down(ce, (unsigned)o, 64);
    if (lane == 0) fred[wv] = ce;

    if (tid < 64) {   // moments + image min/max
        double q0 = mom[(ib * 64 + tid) * 4 + 0];
        double q1 = mom[(ib * 64 + tid) * 4 + 1];
        double q2 = mom[(ib * 64 + tid) * 4 + 2];
        double q3 = mom[(ib * 64 + tid) * 4 + 3];
        uint2 e = mmp[ib * 64 + tid];
        unsigned emn = e.x, emx = e.y;
        for (int o = 32; o; o >>= 1) {
            q0 += __shfl_down(q0, (unsigned)o, 64);
            q1 += __shfl_down(q1, (unsigned)o, 64);
            q2 += __shfl_down(q2, (unsigned)o, 64);
            q3 += __shfl_down(q3, (unsigned)o, 64);
            emn = min(emn, (unsigned)__shfl_down(emn, (unsigned)o, 64));
            emx = max(emx, (unsigned)__shfl_down(emx, (unsigned)o, 64));
        }
        if (tid == 0) {
            smom[0] = q0; smom[1] = q1; smom[2] = q2; smom[3] = q3;
            smm2[0] = emn; smm2[1] = emx;
        }
    }
    {   // global max over all 1024 slice maxima (scale decision)
        unsigned g = max(max(mmp[tid].y, mmp[256 + tid].y),
                         max(mmp[512 + tid].y, mmp[768 + tid].y));
        for (int o = 32; o; o >>= 1)
            g = max(g, (unsigned)__shfl_down(g, (unsigned)o, 64));
        if (lane == 0) sgm[wv] = g;
    }
    __syncthreads();

    if (tid == 0) {
        float ent = -(fred[0] + fred[1] + fred[2] + fred[3]) / 8.f;  // /log2(256)
        float gmax = decf(max(max(sgm[0], sgm[1]), max(sgm[2], sgm[3])));
        float sc = (gmax > 1.f) ? (1.f / 16383.f) : 1.f;
        double N = (double)NPIX;
        double S = smom[0], S2 = smom[1], LS = smom[2], LS2 = smom[3];
        double sc2 = (double)sc * (double)sc;
        float var  = (float)((S2  - S  * S  / N) / (N - 1.0) * sc2);
        float lvar = (float)((LS2 - LS * LS / N) / (N - 1.0) * sc2);
        float mn = decf(smm2[0]) * sc;
        float mx = decf(smm2[1]) * sc;
        float* fo = out + 64 + ib * 5;
        fo[0] = var; fo[1] = mn; fo[2] = mx; fo[3] = ent; fo[4] = lvar;
        f5[0] = var; f5[1] = mn; f5[2] = mx; f5[3] = ent; f5[4] = lvar;
    }
    __syncthreads();

    // tiny MLP
    if (tid < 64) {
        float aa = b1[tid];
        #pragma unroll
        for (int k = 0; k < 5; ++k) aa += W1[tid * 5 + k] * f5[k];
        h1[tid] = fmaxf(aa, 0.f);
    }
    __syncthreads();
    if (tid < 64) {
        float a2 = b2[tid];
        #pragma unroll
        for (int k = 0; k < 64; ++k) a2 += W2[tid * 64 + k] * h1[k];
        h2[tid] = fmaxf(a2, 0.f);
    }
    __syncthreads();
    if (tid < 3) {
        float a3 = b3[tid];
        #pragma unroll
        for (int k = 0; k < 64; ++k) a3 += W3[tid * 64 + k] * h2[k];
        lg[tid] = a3;
    }
    __syncthreads();
    if (tid == 0) {
        float m = fmaxf(lg[0], fmaxf(lg[1], lg[2]));
        float e0 = expf(lg[0] - m), e1 = expf(lg[1] - m), e2 = expf(lg[2] - m);
        float inv = 1.f / (e0 + e1 + e2);
        float p0 = e0 * inv, p1 = e1 * inv, p2 = e2 * inv;
        out[16 + ib * 3 + 0] = p0;
        out[16 + ib * 3 + 1] = p1;
        out[16 + ib * 3 + 2] = p2;
        int cid = 0; float bm = p0;
        if (p1 > bm) { bm = p1; cid = 1; }
        if (p2 > bm) { bm = p2; cid = 2; }
        out[ib] = (float)cid;
    }
}

extern "C" void kernel_launch(void* const* d_in, const int* in_sizes, int n_in,
                              void* d_out, int out_size, void* d_ws, size_t ws_size,
                              hipStream_t stream) {
    const float* img = (const float*)d_in[0];
    const float* W1  = (const float*)d_in[1];
    const float* b1  = (const float*)d_in[2];
    const float* W2  = (const float*)d_in[3];
    const float* b2  = (const float*)d_in[4];
    const float* W3  = (const float*)d_in[5];
    const float* b3  = (const float*)d_in[6];
    float* out = (float*)d_out;

    char* ws = (char*)d_ws;
    uint2*    mmp   = (uint2*)ws;                 // 1024 uint2     (8 KB)
    double*   mom   = (double*)(ws + 8192);       // 1024*4 double  (32 KB)
    unsigned* bhist = (unsigned*)(ws + 40960);    // 1024*256 uint  (1 MB)

    k_minmax<<<NBLK, 256, 0, stream>>>(img, mmp);
    k_main  <<<NBLK, 256, 0, stream>>>(img, mmp, mom, bhist);
    k_final <<<IMG_B, 256, 0, stream>>>(bhist, mom, mmp,
                                        W1, b1, W2, b2, W3, b3, out);
}